// Round 4
// baseline (913.176 us; speedup 1.0000x reference)
//
#include <hip/hip_runtime.h>
#include <hip/hip_bf16.h>

typedef __attribute__((ext_vector_type(8))) short  bf16x8;
typedef __attribute__((ext_vector_type(4))) short  s16x4;
typedef __attribute__((ext_vector_type(4))) float  f32x4;

#define LOG2E 1.44269504088896340736f

template<int N> struct ic { static constexpr int v = N; };

__device__ __forceinline__ unsigned short f2bf(float x) {
    union { float f; unsigned int u; } v; v.f = x;
    unsigned int u = v.u;
    u += 0x7fffu + ((u >> 16) & 1u);          // round-to-nearest-even
    return (unsigned short)(u >> 16);
}

__device__ __forceinline__ float fast_sigmoid(float x) {
    float e = __builtin_amdgcn_exp2f(-LOG2E * x);
    return __builtin_amdgcn_rcpf(1.0f + e);
}
__device__ __forceinline__ float fast_tanh(float x) {
    float e = __builtin_amdgcn_exp2f(2.0f * LOG2E * x);
    return 1.0f - 2.0f * __builtin_amdgcn_rcpf(1.0f + e);
}

// ---------------------------------------------------------------------------
// Pack [1024 x 256] fp32 weight into bf16 MFMA-B-fragment-major layout.
//   fid = w*64 + kk*8 + j ; dst[(fid*64+lane)*8+e] = bf16(W[R][k])
//   R = g*256 + w*32 + tn*16 + (lane&15), j = g*2+tn
//   k = kk*32 + 4*(lane>>4) + (e&3) + 16*(e>>2)
// ---------------------------------------------------------------------------
__global__ void pack_w_big(const float* __restrict__ W, unsigned short* __restrict__ dst) {
    int idx  = blockIdx.x * 256 + threadIdx.x;   // 0..32767
    int lane = idx & 63;
    int fid  = idx >> 6;                         // 0..511
    int j    = fid & 7;
    int kk   = (fid >> 3) & 7;
    int w    = fid >> 6;
    int g    = j >> 1, tn = j & 1;
    int R    = g * 256 + w * 32 + tn * 16 + (lane & 15);
    int kb   = kk * 32 + 4 * (lane >> 4);
    const float* src = W + (size_t)R * 256 + kb;
    union { unsigned short s[8]; uint4 v; } u;
#pragma unroll
    for (int e = 0; e < 8; ++e) {
        int k = (e & 3) + 16 * (e >> 2);
        u.s[e] = f2bf(src[k]);
    }
    *(uint4*)(dst + (size_t)idx * 8) = u.v;
}

// W_out [128 x 256]: fid = wv*8 + kk, R = wv*16 + (lane&15)
__global__ void pack_w_out(const float* __restrict__ W, unsigned short* __restrict__ dst) {
    int idx  = blockIdx.x * 256 + threadIdx.x;   // 0..4095
    int lane = idx & 63;
    int fid  = idx >> 6;                         // 0..63
    int kk   = fid & 7;
    int wv   = fid >> 3;
    int R    = wv * 16 + (lane & 15);
    int kb   = kk * 32 + 4 * (lane >> 4);
    const float* src = W + (size_t)R * 256 + kb;
    union { unsigned short s[8]; uint4 v; } u;
#pragma unroll
    for (int e = 0; e < 8; ++e) {
        int k = (e & 3) + 16 * (e >> 2);
        u.s[e] = f2bf(src[k]);
    }
    *(uint4*)(dst + (size_t)idx * 8) = u.v;
}

// ---------------------------------------------------------------------------
// Persistent LSTM. 128 blocks x 512 thr (8 waves). Wave w owns gate strip
// [w*32,+32) x {i,f,g,o} and y cols [w*16,+16).
// Whh residency: kk0..3 in registers (128 VGPR), kk4 parked in LDS (64 KB),
// kk5/6/7 streamed per step through one 64 KB LDS buffer via
// global_load_lds (no VGPR cost), consumed at phases 1/4/7 so every reissue
// has >=2 phases (~300cy) of slack. Raw s_barrier (no vmcnt drain) keeps the
// cross-step kk5 prefetch in flight.
// ---------------------------------------------------------------------------
__global__ __launch_bounds__(512, 2) void lstm_main(
    const float* __restrict__ C,
    const unsigned short* __restrict__ Wih_p,
    const unsigned short* __restrict__ Whh_p,
    const unsigned short* __restrict__ Wout_p,
    const float* __restrict__ b_ih,
    const float* __restrict__ b_hh,
    const float* __restrict__ b_out,
    float* __restrict__ Y,
    int T, int Btot)
{
    __shared__ short hbuf[2][16 * 256];     // 16 KB (h double-buffer)
    __shared__ short wpark[8][8][512];      // 64 KB: kk4 B-frags, per wave
    __shared__ short wstream[8][8][512];    // 64 KB: rotating kk5/6/7 buffer

    const int tid  = threadIdx.x;
    const int l    = tid & 63;
    const int wid  = tid >> 6;     // 0..7
    const int l15  = l & 15;
    const int g4   = l >> 4;       // 0..3
    const int row0 = blockIdx.x * 16;

    const unsigned short* wib = Wih_p + (size_t)wid * 32768;
    const unsigned short* whb = Whh_p + (size_t)wid * 32768;

    // ---- stage C tile -> hbuf[0] (bf16, swizzled 8B slots) ----
    {
        int r  = tid >> 5;         // 0..15
        int cb = tid & 31;         // 8-col block
        const float* src = C + (size_t)(row0 + r) * 256 + cb * 8;
        float4 f0 = *(const float4*)(src);
        float4 f1 = *(const float4*)(src + 4);
        int m  = 9 * (r & 7);
        int s0 = cb * 2;
        short* hb = hbuf[0] + r * 256;
        union { unsigned short s[4]; unsigned long long v; } p0, p1;
        p0.s[0] = f2bf(f0.x); p0.s[1] = f2bf(f0.y); p0.s[2] = f2bf(f0.z); p0.s[3] = f2bf(f0.w);
        p1.s[0] = f2bf(f1.x); p1.s[1] = f2bf(f1.y); p1.s[2] = f2bf(f1.z); p1.s[3] = f2bf(f1.w);
        *(unsigned long long*)(hb + ((s0 ^ m) * 4))       = p0.v;
        *(unsigned long long*)(hb + (((s0 + 1) ^ m) * 4)) = p1.v;
    }

    // async weight staging: kk4 -> park, kk5 -> stream (both land at the
    // prologue __syncthreads)
    auto issue_slice = [&](short (*dstw)[512], int kk) {
#pragma unroll
        for (int j = 0; j < 8; ++j) {
            const unsigned short* src = whb + (((size_t)kk * 8 + j) * 64 + l) * 8;
            __builtin_amdgcn_global_load_lds(
                (const __attribute__((address_space(1))) void*)src,
                (__attribute__((address_space(3))) void*)&dstw[j][0],
                16, 0, 0);
        }
    };
    issue_slice(wpark[wid],   4);
    issue_slice(wstream[wid], 5);

    // A-frag loader: row = l&15, k = kk*32 + 4*(l>>4) + {0..3,16..19}
    const int msw = 9 * (l15 & 7);
    auto loadA = [&](const short* buf, int kk) -> bf16x8 {
        int slo = kk * 8 + g4;
        const short* base = buf + l15 * 256;
        s16x4 lo = *(const s16x4*)(base + ((slo ^ msw) * 4));
        s16x4 hi = *(const s16x4*)(base + (((slo + 4) ^ msw) * 4));
        bf16x8 a;
        a[0] = lo[0]; a[1] = lo[1]; a[2] = lo[2]; a[3] = lo[3];
        a[4] = hi[0]; a[5] = hi[1]; a[6] = hi[2]; a[7] = hi[3];
        return a;
    };
    auto loadB = [&](const unsigned short* wb, int kk, int j) -> bf16x8 {
        return *(const bf16x8*)(wb + (((size_t)kk * 8 + j) * 64 + l) * 8);
    };

    __syncthreads();   // C tile + park/stream staging complete

    // ---- x_gates = C @ W_ih^T + biases (one-time; simple unrolled GEMM) ----
    f32x4 acc[8];
#pragma unroll
    for (int j = 0; j < 8; ++j) acc[j] = (f32x4){0.f, 0.f, 0.f, 0.f};
#pragma unroll
    for (int kk = 0; kk < 8; ++kk) {
        bf16x8 a = loadA(hbuf[0], kk);
#pragma unroll
        for (int j = 0; j < 8; ++j)
            acc[j] = __builtin_amdgcn_mfma_f32_16x16x32_bf16(a, loadB(wib, kk, j), acc[j], 0, 0, 0);
    }
    f32x4 xg[8];
#pragma unroll
    for (int j = 0; j < 8; ++j) {
        int g = j >> 1, tn = j & 1;
        int col = g * 256 + wid * 32 + tn * 16 + l15;
        xg[j] = acc[j] + (b_ih[col] + b_hh[col]);
    }

    // ---- register-resident weights: Whh kk0..3 + W_out ----
    bf16x8 r[4][8];
#pragma unroll
    for (int kk = 0; kk < 4; ++kk)
#pragma unroll
        for (int j = 0; j < 8; ++j) r[kk][j] = loadB(whb, kk, j);
    bf16x8 wout[8];
#pragma unroll
    for (int kk = 0; kk < 8; ++kk)
        wout[kk] = *(const bf16x8*)(Wout_p + ((size_t)(wid * 8 + kk) * 64 + l) * 8);

    float cst[8];
#pragma unroll
    for (int i = 0; i < 8; ++i) cst[i] = 0.f;
    const float by = b_out[wid * 16 + l15];

    auto update_write = [&](short* nxtb) {
#pragma unroll
        for (int tn = 0; tn < 2; ++tn) {
#pragma unroll
            for (int rr = 0; rr < 4; ++rr) {
                float iv = fast_sigmoid(acc[0 + tn][rr]);
                float fv = fast_sigmoid(acc[2 + tn][rr]);
                float gv = fast_tanh(acc[4 + tn][rr]);
                float ov = fast_sigmoid(acc[6 + tn][rr]);
                float cn = fv * cst[tn * 4 + rr] + iv * gv;
                cst[tn * 4 + rr] = cn;
                float hn = ov * fast_tanh(cn);
                int row = 4 * g4 + rr;
                int col = wid * 32 + tn * 16 + l15;
                int ps  = (col >> 2) ^ (9 * (row & 7));
                nxtb[row * 256 + ps * 4 + (col & 3)] = (short)f2bf(hn);
            }
        }
    };

    // ---- t = 0: gates = x_gates (h0 = 0); then pack xg to bf16 ----
#pragma unroll
    for (int j = 0; j < 8; ++j) acc[j] = xg[j];
    update_write(hbuf[1]);

    unsigned xgp[16];
#pragma unroll
    for (int j = 0; j < 8; ++j) {
        xgp[2 * j]     = (unsigned)f2bf(xg[j][0]) | ((unsigned)f2bf(xg[j][1]) << 16);
        xgp[2 * j + 1] = (unsigned)f2bf(xg[j][2]) | ((unsigned)f2bf(xg[j][3]) << 16);
    }
    __syncthreads();

    auto xgu = [&](int j) -> f32x4 {
        union { unsigned u; float f; } c0, c1, c2, c3;
        unsigned u0 = xgp[2 * j], u1 = xgp[2 * j + 1];
        c0.u = u0 << 16; c1.u = u0 & 0xffff0000u;
        c2.u = u1 << 16; c3.u = u1 & 0xffff0000u;
        return (f32x4){c0.f, c1.f, c2.f, c3.f};
    };

    f32x4 accy;

    // resident-slice phase (kk0..3); FIRST seeds acc from xg, accy from bias
    auto phaseR = [&](auto firstc, auto kkc, const short* curb) {
        constexpr int first = decltype(firstc)::v;
        constexpr int kk    = decltype(kkc)::v;
        bf16x8 a = loadA(curb, kk);
        if constexpr (first)
            accy = __builtin_amdgcn_mfma_f32_16x16x32_bf16(a, wout[kk], (f32x4){by, by, by, by}, 0, 0, 0);
        else
            accy = __builtin_amdgcn_mfma_f32_16x16x32_bf16(a, wout[kk], accy, 0, 0, 0);
#pragma unroll
        for (int j = 0; j < 8; ++j) {
            if constexpr (first)
                acc[j] = __builtin_amdgcn_mfma_f32_16x16x32_bf16(a, r[kk][j], xgu(j), 0, 0, 0);
            else
                acc[j] = __builtin_amdgcn_mfma_f32_16x16x32_bf16(a, r[kk][j], acc[j], 0, 0, 0);
        }
    };
    // LDS-sourced phase (park or stream buffer)
    auto phaseL = [&](auto kkc, const short* curb, const short (*wsl)[512]) {
        constexpr int kk = decltype(kkc)::v;
        bf16x8 a = loadA(curb, kk);
        accy = __builtin_amdgcn_mfma_f32_16x16x32_bf16(a, wout[kk], accy, 0, 0, 0);
#pragma unroll
        for (int j = 0; j < 8; ++j) {
            bf16x8 b = *(const bf16x8*)&wsl[j][l * 8];
            acc[j] = __builtin_amdgcn_mfma_f32_16x16x32_bf16(a, b, acc[j], 0, 0, 0);
        }
    };

#define WAITV asm volatile("s_waitcnt vmcnt(0)" ::: "memory")
#define WAITL asm volatile("s_waitcnt lgkmcnt(0)" ::: "memory")

    // ---- main loop t = 1..T-1 ----
    for (int t = 1; t < T; ++t) {
        const short* curb = hbuf[t & 1];
        short*       nxtb = hbuf[(t + 1) & 1];

        phaseR(ic<1>{}, ic<0>{}, curb);                    // ph0: kk0
        WAITV; phaseL(ic<5>{}, curb, wstream[wid]);        // ph1: kk5 (stream)
        WAITL; issue_slice(wstream[wid], 6);               //   S <- kk6
        phaseR(ic<0>{}, ic<1>{}, curb);                    // ph2: kk1
        phaseR(ic<0>{}, ic<2>{}, curb);                    // ph3: kk2
        WAITV; phaseL(ic<6>{}, curb, wstream[wid]);        // ph4: kk6 (stream)
        WAITL; issue_slice(wstream[wid], 7);               //   S <- kk7
        phaseR(ic<0>{}, ic<3>{}, curb);                    // ph5: kk3
        phaseL(ic<4>{}, curb, wpark[wid]);                 // ph6: kk4 (park)
        WAITV; phaseL(ic<7>{}, curb, wstream[wid]);        // ph7: kk7 (stream)
        WAITL; issue_slice(wstream[wid], 5);               //   S <- kk5 (next t)

        // store y_{t-1} = h_t @ W_out^T + b_out
        {
            float* yp = Y + ((size_t)(t - 1) * Btot + row0 + 4 * g4) * 128 + wid * 16 + l15;
#pragma unroll
            for (int rr = 0; rr < 4; ++rr)
                __builtin_nontemporal_store(accy[rr], yp + (size_t)rr * 128);
        }
        update_write(nxtb);

        // raw barrier: h writes visible, weight prefetch stays in flight
        WAITL;
        __builtin_amdgcn_sched_barrier(0);
        __builtin_amdgcn_s_barrier();
    }

    // ---- epilogue: y_{T-1} = h_T @ W_out^T + b_out ----
    {
        const short* curb = hbuf[T & 1];
        accy = (f32x4){by, by, by, by};
#pragma unroll
        for (int kk = 0; kk < 8; ++kk) {
            bf16x8 a = loadA(curb, kk);
            accy = __builtin_amdgcn_mfma_f32_16x16x32_bf16(a, wout[kk], accy, 0, 0, 0);
        }
        float* yp = Y + ((size_t)(T - 1) * Btot + row0 + 4 * g4) * 128 + wid * 16 + l15;
#pragma unroll
        for (int rr = 0; rr < 4; ++rr)
            __builtin_nontemporal_store(accy[rr], yp + (size_t)rr * 128);
    }
#undef WAITV
#undef WAITL
}

extern "C" void kernel_launch(void* const* d_in, const int* in_sizes, int n_in,
                              void* d_out, int out_size, void* d_ws, size_t ws_size,
                              hipStream_t stream) {
    const float* C     = (const float*)d_in[0];
    const float* W_ih  = (const float*)d_in[1];
    const float* W_hh  = (const float*)d_in[2];
    const float* b_ih  = (const float*)d_in[3];
    const float* b_hh  = (const float*)d_in[4];
    const float* W_out = (const float*)d_in[5];
    const float* b_out = (const float*)d_in[6];

    const int H    = 256;
    const int Btot = in_sizes[0] / H;     // 2048
    const int O    = in_sizes[5] / H;     // 128
    const int T    = out_size / (Btot * O);

    unsigned short* Whh_p  = (unsigned short*)d_ws;          // 512 KB
    unsigned short* Wih_p  = Whh_p + (1 << 18);              // 512 KB
    unsigned short* Wout_p = Wih_p + (1 << 18);              // 64 KB

    hipLaunchKernelGGL(pack_w_big, dim3(128), dim3(256), 0, stream, W_hh, Whh_p);
    hipLaunchKernelGGL(pack_w_big, dim3(128), dim3(256), 0, stream, W_ih, Wih_p);
    hipLaunchKernelGGL(pack_w_out, dim3(16),  dim3(256), 0, stream, W_out, Wout_p);
    hipLaunchKernelGGL(lstm_main, dim3(Btot / 16), dim3(512), 0, stream,
                       C, Wih_p, Whh_p, Wout_p, b_ih, b_hh, b_out,
                       (float*)d_out, T, Btot);
}